// Round 1
// baseline (2067.657 us; speedup 1.0000x reference)
//
#include <hip/hip_runtime.h>
#include <math.h>

#define SEQ 4096
#define DM  1024
#define NH  16
#define DK  64
#define HDK 32   // DK/2

// ---------------------------------------------------------------------------
// C = A * W^T.  A: [M][K] row-major. W: [N][K] row-major.
// MODE 0: plain store C[m][n]                       (used for the Wo proj)
// MODE 1: head-split store C[((n>>6)*M + m)*64 + (n&63)]          (V proj)
// MODE 2: head-split store + fused RoPE                         (Q/K proj)
// Tiling: 128x128x16, 256 threads, 8x8 micro-tile per thread.
// LDS tiles stored K-major ([16][128+4]) so the inner loop reads float4.
// ---------------------------------------------------------------------------
template<int MODE>
__global__ __launch_bounds__(256)
void gemm_xwt(const float* __restrict__ A, const float* __restrict__ W,
              float* __restrict__ C,
              const float* __restrict__ cosT, const float* __restrict__ sinT,
              const int* __restrict__ positions,
              int M, int N, int K)
{
    __shared__ float As[16][132];   // stride 132 floats = 528B, 16B-aligned rows
    __shared__ float Bs[16][132];

    const int t  = threadIdx.x;
    const int tx = t & 15;          // n-group (8 cols each)
    const int ty = t >> 4;          // m-group (8 rows each)
    const int m0 = blockIdx.y * 128;
    const int n0 = blockIdx.x * 128;

    float acc[8][8];
#pragma unroll
    for (int i = 0; i < 8; ++i)
#pragma unroll
        for (int j = 0; j < 8; ++j) acc[i][j] = 0.0f;

    for (int k0 = 0; k0 < K; k0 += 16) {
        // Stage A-tile and W-tile (each 128 rows x 16 k) transposed into LDS.
#pragma unroll
        for (int u = 0; u < 2; ++u) {
            const int f4 = u * 256 + t;       // 0..511 float4 slots
            const int mm = f4 >> 2;           // tile row 0..127
            const int kc = (f4 & 3) * 4;      // k offset 0,4,8,12
            const float4 av = *reinterpret_cast<const float4*>(
                &A[(size_t)(m0 + mm) * K + k0 + kc]);
            As[kc + 0][mm] = av.x; As[kc + 1][mm] = av.y;
            As[kc + 2][mm] = av.z; As[kc + 3][mm] = av.w;
            const float4 bv = *reinterpret_cast<const float4*>(
                &W[(size_t)(n0 + mm) * K + k0 + kc]);
            Bs[kc + 0][mm] = bv.x; Bs[kc + 1][mm] = bv.y;
            Bs[kc + 2][mm] = bv.z; Bs[kc + 3][mm] = bv.w;
        }
        __syncthreads();
#pragma unroll
        for (int kk = 0; kk < 16; ++kk) {
            const float4 a0 = *reinterpret_cast<const float4*>(&As[kk][ty * 8]);
            const float4 a1 = *reinterpret_cast<const float4*>(&As[kk][ty * 8 + 4]);
            const float4 b0 = *reinterpret_cast<const float4*>(&Bs[kk][tx * 8]);
            const float4 b1 = *reinterpret_cast<const float4*>(&Bs[kk][tx * 8 + 4]);
            const float a[8] = {a0.x, a0.y, a0.z, a0.w, a1.x, a1.y, a1.z, a1.w};
            const float b[8] = {b0.x, b0.y, b0.z, b0.w, b1.x, b1.y, b1.z, b1.w};
#pragma unroll
            for (int i = 0; i < 8; ++i)
#pragma unroll
                for (int j = 0; j < 8; ++j)
                    acc[i][j] = fmaf(a[i], b[j], acc[i][j]);
        }
        __syncthreads();
    }

    // Epilogue
    const int nb = n0 + tx * 8;   // 8 consecutive n; never crosses a 64-boundary
#pragma unroll
    for (int i = 0; i < 8; ++i) {
        const int m = m0 + ty * 8 + i;
        float vals[8];
#pragma unroll
        for (int j = 0; j < 8; ++j) vals[j] = acc[i][j];
        if (MODE == 2) {
            const int pos = positions[m];
            const int pg0 = (nb & 63) >> 1;
#pragma unroll
            for (int p = 0; p < 4; ++p) {
                const float cc = cosT[pos * HDK + pg0 + p];
                const float ss = sinT[pos * HDK + pg0 + p];
                const float x1 = vals[2 * p], x2 = vals[2 * p + 1];
                vals[2 * p]     = x1 * cc - x2 * ss;
                vals[2 * p + 1] = x1 * ss + x2 * cc;
            }
        }
        float* cp;
        if (MODE == 0) {
            cp = &C[(size_t)m * N + nb];
        } else {
            cp = &C[((size_t)(nb >> 6) * M + m) * DK + (nb & 63)];
        }
        *reinterpret_cast<float4*>(cp)     = make_float4(vals[0], vals[1], vals[2], vals[3]);
        *reinterpret_cast<float4*>(cp + 4) = make_float4(vals[4], vals[5], vals[6], vals[7]);
    }
}

// ---------------------------------------------------------------------------
// Flash-style causal attention, fp32.
// Q,K,V layout: [head][seq][64]. One block = (head, 64-row q-tile).
// Per key-tile: phase A computes S=QK^T (4x4 register tile per thread,
// strided row/col assignment keeps LDS reads <=2-way conflicted), phase B
// does online softmax + PV accumulation (1 q-row x 16 dims per thread).
// Output written as Y[seq][1024] (head-interleaved) for the Wo GEMM.
// ---------------------------------------------------------------------------
__global__ __launch_bounds__(256)
void attn_kernel(const float* __restrict__ Q, const float* __restrict__ K,
                 const float* __restrict__ V, float* __restrict__ Y)
{
    __shared__ float Qs[64][68];
    __shared__ float Ks[64][68];
    __shared__ float Vs[64][68];
    __shared__ float Ss[64][68];

    const int t  = threadIdx.x;
    const int qt = blockIdx.x;
    const int h  = blockIdx.y;

    const int rg = t >> 4;   // phase A row group (rows rg, rg+16, rg+32, rg+48)
    const int cg = t & 15;   // phase A col group (cols cg, cg+16, cg+32, cg+48)
    const int r  = t >> 2;   // phase B q-row 0..63
    const int bq = t & 3;    // phase B dim quarter (16 dims)

    // Load Q tile (64x64) into LDS.
    const float* qb = Q + ((size_t)h * SEQ + (size_t)qt * 64) * DK;
#pragma unroll
    for (int u = 0; u < 4; ++u) {
        const int f4 = u * 256 + t;
        const int mm = f4 >> 4;
        const int c4 = (f4 & 15) * 4;
        *reinterpret_cast<float4*>(&Qs[mm][c4]) =
            *reinterpret_cast<const float4*>(&qb[(size_t)mm * DK + c4]);
    }

    float4 O4[4];
    O4[0] = O4[1] = O4[2] = O4[3] = make_float4(0.f, 0.f, 0.f, 0.f);
    float m_run = -1e30f, l_run = 0.0f;

    for (int kt = 0; kt <= qt; ++kt) {
        __syncthreads();   // Q visible (iter 0); prev phase B done with Ks/Vs/Ss
        const float* kb = K + ((size_t)h * SEQ + (size_t)kt * 64) * DK;
        const float* vb = V + ((size_t)h * SEQ + (size_t)kt * 64) * DK;
#pragma unroll
        for (int u = 0; u < 4; ++u) {
            const int f4 = u * 256 + t;
            const int mm = f4 >> 4;
            const int c4 = (f4 & 15) * 4;
            *reinterpret_cast<float4*>(&Ks[mm][c4]) =
                *reinterpret_cast<const float4*>(&kb[(size_t)mm * DK + c4]);
            *reinterpret_cast<float4*>(&Vs[mm][c4]) =
                *reinterpret_cast<const float4*>(&vb[(size_t)mm * DK + c4]);
        }
        __syncthreads();

        // ---- Phase A: S = Q K^T (scaled, masked) ----
        float acc[4][4];
#pragma unroll
        for (int i = 0; i < 4; ++i)
#pragma unroll
            for (int j = 0; j < 4; ++j) acc[i][j] = 0.0f;

#pragma unroll
        for (int d4 = 0; d4 < 16; ++d4) {
            float4 qv[4], kv[4];
#pragma unroll
            for (int i = 0; i < 4; ++i)
                qv[i] = *reinterpret_cast<const float4*>(&Qs[rg + 16 * i][d4 * 4]);
#pragma unroll
            for (int j = 0; j < 4; ++j)
                kv[j] = *reinterpret_cast<const float4*>(&Ks[cg + 16 * j][d4 * 4]);
#pragma unroll
            for (int i = 0; i < 4; ++i)
#pragma unroll
                for (int j = 0; j < 4; ++j)
                    acc[i][j] += qv[i].x * kv[j].x + qv[i].y * kv[j].y
                               + qv[i].z * kv[j].z + qv[i].w * kv[j].w;
        }

        const int kbase = kt * 64;
#pragma unroll
        for (int i = 0; i < 4; ++i) {
            const int rr = rg + 16 * i;
            const int qglob = qt * 64 + rr;
#pragma unroll
            for (int j = 0; j < 4; ++j) {
                const int cc = cg + 16 * j;
                float sv = acc[i][j] * 0.125f;       // 1/sqrt(64)
                if (kbase + cc > qglob) sv = -1e30f; // causal mask
                Ss[rr][cc] = sv;
            }
        }
        __syncthreads();

        // ---- Phase B: online softmax + P*V ----
        float mx = m_run;
#pragma unroll 8
        for (int c = 0; c < 64; ++c) mx = fmaxf(mx, Ss[r][c]);
        const float factor = __expf(m_run - mx);
        l_run *= factor;
#pragma unroll
        for (int u = 0; u < 4; ++u) {
            O4[u].x *= factor; O4[u].y *= factor;
            O4[u].z *= factor; O4[u].w *= factor;
        }
#pragma unroll 4
        for (int c = 0; c < 64; ++c) {
            const float p = __expf(Ss[r][c] - mx);
            l_run += p;
            const float4* vp = reinterpret_cast<const float4*>(&Vs[c][bq * 16]);
#pragma unroll
            for (int u = 0; u < 4; ++u) {
                const float4 vv = vp[u];
                O4[u].x += p * vv.x; O4[u].y += p * vv.y;
                O4[u].z += p * vv.z; O4[u].w += p * vv.w;
            }
        }
        m_run = mx;
    }

    const float inv = 1.0f / l_run;
    float* yp = &Y[(size_t)(qt * 64 + r) * DM + h * DK + bq * 16];
#pragma unroll
    for (int u = 0; u < 4; ++u) {
        float4 o = O4[u];
        o.x *= inv; o.y *= inv; o.z *= inv; o.w *= inv;
        reinterpret_cast<float4*>(yp)[u] = o;
    }
}

// ---------------------------------------------------------------------------
extern "C" void kernel_launch(void* const* d_in, const int* in_sizes, int n_in,
                              void* d_out, int out_size, void* d_ws, size_t ws_size,
                              hipStream_t stream)
{
    const float* x    = (const float*)d_in[0];
    const float* Wq   = (const float*)d_in[1];
    const float* Wk   = (const float*)d_in[2];
    const float* Wv   = (const float*)d_in[3];
    const float* Wo   = (const float*)d_in[4];
    const float* cosT = (const float*)d_in[5];
    const float* sinT = (const float*)d_in[6];
    const int*   pos  = (const int*)d_in[7];
    float* out = (float*)d_out;

    // Workspace: Q, K, V in [head][seq][64] layout, Y in [seq][1024]. 64 MB.
    float* q = (float*)d_ws;
    float* k = q + (size_t)SEQ * DM;
    float* v = k + (size_t)SEQ * DM;
    float* y = v + (size_t)SEQ * DM;

    dim3 gg(DM / 128, SEQ / 128), bb(256);
    gemm_xwt<2><<<gg, bb, 0, stream>>>(x, Wq, q, cosT, sinT, pos, SEQ, DM, DM);
    gemm_xwt<2><<<gg, bb, 0, stream>>>(x, Wk, k, cosT, sinT, pos, SEQ, DM, DM);
    gemm_xwt<1><<<gg, bb, 0, stream>>>(x, Wv, v, cosT, sinT, pos, SEQ, DM, DM);
    attn_kernel<<<dim3(SEQ / 64, NH), bb, 0, stream>>>(q, k, v, y);
    gemm_xwt<0><<<gg, bb, 0, stream>>>(y, Wo, out, cosT, sinT, pos, SEQ, DM, DM);
}

// Round 2
// 688.039 us; speedup vs baseline: 3.0051x; 3.0051x over previous
//
#include <hip/hip_runtime.h>
#include <math.h>

#define SEQ 4096
#define DM  1024
#define NH  16
#define DK  64
#define HDK 32   // DK/2

typedef __attribute__((ext_vector_type(4))) float f32x4;
typedef __attribute__((ext_vector_type(8))) short bf16x8;     // 8 bf16 (4 VGPRs)
typedef __attribute__((ext_vector_type(8))) unsigned short u16x8;

__device__ __forceinline__ unsigned short f2bf(float f) {
    union { float f; unsigned u; } v; v.f = f;
    unsigned r = v.u + 0x7fffu + ((v.u >> 16) & 1u);   // RNE
    return (unsigned short)(r >> 16);
}
__device__ __forceinline__ float bf2f(unsigned short s) {
    union { unsigned u; float f; } v; v.u = ((unsigned)s) << 16;
    return v.f;
}

// ---------------------------------------------------------------------------
// C = A * W^T.  A: [M][K] row-major. W: [N][K] row-major.
// MODE 0: fp32 store C[m][n]                                     (Wo proj)
// MODE 1: bf16 hi/lo TRANSPOSED store Ct[n][m]                   (V proj)
// MODE 2: bf16 hi/lo head-split store + RoPE + 1/8 scale         (Q proj)
// MODE 3: bf16 hi/lo head-split store + RoPE                     (K proj)
// Tiling: 128x128x16, 256 threads, 8x8 micro-tile per thread.
// ---------------------------------------------------------------------------
template<int MODE>
__global__ __launch_bounds__(256)
void gemm_xwt(const float* __restrict__ A, const float* __restrict__ W,
              void* __restrict__ Cv0, void* __restrict__ Cv1,
              const float* __restrict__ cosT, const float* __restrict__ sinT,
              const int* __restrict__ positions,
              int M, int N, int K)
{
    __shared__ float As[16][132];
    __shared__ float Bs[16][132];

    const int t  = threadIdx.x;
    const int tx = t & 15;
    const int ty = t >> 4;
    const int m0 = blockIdx.y * 128;
    const int n0 = blockIdx.x * 128;

    float acc[8][8];
#pragma unroll
    for (int i = 0; i < 8; ++i)
#pragma unroll
        for (int j = 0; j < 8; ++j) acc[i][j] = 0.0f;

    for (int k0 = 0; k0 < K; k0 += 16) {
#pragma unroll
        for (int u = 0; u < 2; ++u) {
            const int f4 = u * 256 + t;
            const int mm = f4 >> 2;
            const int kc = (f4 & 3) * 4;
            const float4 av = *reinterpret_cast<const float4*>(
                &A[(size_t)(m0 + mm) * K + k0 + kc]);
            As[kc + 0][mm] = av.x; As[kc + 1][mm] = av.y;
            As[kc + 2][mm] = av.z; As[kc + 3][mm] = av.w;
            const float4 bv = *reinterpret_cast<const float4*>(
                &W[(size_t)(n0 + mm) * K + k0 + kc]);
            Bs[kc + 0][mm] = bv.x; Bs[kc + 1][mm] = bv.y;
            Bs[kc + 2][mm] = bv.z; Bs[kc + 3][mm] = bv.w;
        }
        __syncthreads();
#pragma unroll
        for (int kk = 0; kk < 16; ++kk) {
            const float4 a0 = *reinterpret_cast<const float4*>(&As[kk][ty * 8]);
            const float4 a1 = *reinterpret_cast<const float4*>(&As[kk][ty * 8 + 4]);
            const float4 b0 = *reinterpret_cast<const float4*>(&Bs[kk][tx * 8]);
            const float4 b1 = *reinterpret_cast<const float4*>(&Bs[kk][tx * 8 + 4]);
            const float a[8] = {a0.x, a0.y, a0.z, a0.w, a1.x, a1.y, a1.z, a1.w};
            const float b[8] = {b0.x, b0.y, b0.z, b0.w, b1.x, b1.y, b1.z, b1.w};
#pragma unroll
            for (int i = 0; i < 8; ++i)
#pragma unroll
                for (int j = 0; j < 8; ++j)
                    acc[i][j] = fmaf(a[i], b[j], acc[i][j]);
        }
        __syncthreads();
    }

    const int nb = n0 + tx * 8;   // 8 consecutive n; never crosses a 64-boundary

    if (MODE == 1) {
        // Transposed bf16 hi/lo store: Ct[n][m], n-major rows of length SEQ.
        unsigned short* Chi = (unsigned short*)Cv0;
        unsigned short* Clo = (unsigned short*)Cv1;
#pragma unroll
        for (int j = 0; j < 8; ++j) {
            u16x8 hv, lv;
#pragma unroll
            for (int i = 0; i < 8; ++i) {
                const float f = acc[i][j];
                const unsigned short hh = f2bf(f);
                hv[i] = hh;
                lv[i] = f2bf(f - bf2f(hh));
            }
            const size_t off = (size_t)(nb + j) * SEQ + (m0 + ty * 8);
            *reinterpret_cast<u16x8*>(&Chi[off]) = hv;
            *reinterpret_cast<u16x8*>(&Clo[off]) = lv;
        }
        return;
    }

#pragma unroll
    for (int i = 0; i < 8; ++i) {
        const int m = m0 + ty * 8 + i;
        float vals[8];
#pragma unroll
        for (int j = 0; j < 8; ++j) vals[j] = acc[i][j];

        if (MODE == 2 || MODE == 3) {
            const int pos = positions[m];
            const int pg0 = (nb & 63) >> 1;
#pragma unroll
            for (int p = 0; p < 4; ++p) {
                const float cc = cosT[pos * HDK + pg0 + p];
                const float ss = sinT[pos * HDK + pg0 + p];
                const float x1 = vals[2 * p], x2 = vals[2 * p + 1];
                vals[2 * p]     = x1 * cc - x2 * ss;
                vals[2 * p + 1] = x1 * ss + x2 * cc;
            }
            if (MODE == 2) {
#pragma unroll
                for (int j = 0; j < 8; ++j) vals[j] *= 0.125f;  // 1/sqrt(dk)
            }
            unsigned short* Chi = (unsigned short*)Cv0;
            unsigned short* Clo = (unsigned short*)Cv1;
            u16x8 hv, lv;
#pragma unroll
            for (int j = 0; j < 8; ++j) {
                const unsigned short hh = f2bf(vals[j]);
                hv[j] = hh;
                lv[j] = f2bf(vals[j] - bf2f(hh));
            }
            const size_t off = ((size_t)(nb >> 6) * SEQ + m) * DK + (nb & 63);
            *reinterpret_cast<u16x8*>(&Chi[off]) = hv;
            *reinterpret_cast<u16x8*>(&Clo[off]) = lv;
        } else {
            float* Cf = (float*)Cv0;
            float* cp = &Cf[(size_t)m * N + nb];
            *reinterpret_cast<float4*>(cp)     = make_float4(vals[0], vals[1], vals[2], vals[3]);
            *reinterpret_cast<float4*>(cp + 4) = make_float4(vals[4], vals[5], vals[6], vals[7]);
        }
    }
}

// ---------------------------------------------------------------------------
// MFMA flash attention, bf16 hi/lo 3-term emulation (fp32-level accuracy).
// Q,K: [head][seq][64] bf16 (hi,lo), Q pre-scaled by 1/8, RoPE'd.
// V:   [head*64+dout][seq] bf16 (hi,lo)  (pre-transposed by the V GEMM).
// Block = 256 thr = 4 waves; wave w owns q rows [w*16, w*16+16) of a 64-row
// q-tile. Each block processes q-tile pair (bx, 63-bx) -> uniform 65 KV tiles.
// S^T = K*Q^T so softmax is in-register (per-lane q = lane&15) and the exp'd
// S^T C-registers are directly the PV A-operand fragments.
// ---------------------------------------------------------------------------
__global__ __launch_bounds__(256)
void attn_mfma(const unsigned short* __restrict__ Qhi, const unsigned short* __restrict__ Qlo,
               const unsigned short* __restrict__ Khi, const unsigned short* __restrict__ Klo,
               const unsigned short* __restrict__ Vhi, const unsigned short* __restrict__ Vlo,
               float* __restrict__ Y)
{
    __shared__ unsigned short KsH[64][68], KsL[64][68];   // [key][d], pitch 68
    __shared__ unsigned short VsH[64][68], VsL[64][68];   // [dout][key], pitch 68

    const int t    = threadIdx.x;
    const int lane = t & 63;
    const int w    = t >> 6;          // wave 0..3
    // XCD swizzle: head h -> XCD h/2 (per-head K/V = 2MB, 2 heads fill one L2)
    const int bid = blockIdx.x;
    const int h   = 2 * (bid & 7) + ((bid >> 3) >> 5);
    const int bx  = (bid >> 3) & 31;

    const int l15 = lane & 15;
    const int lg  = lane >> 4;        // lane group 0..3
    const int dg  = lg * 4;

#pragma unroll 1
    for (int pass = 0; pass < 2; ++pass) {
        const int qt = pass ? (63 - bx) : bx;

        // Q fragments for this wave's 16 rows (lane: q = l15, d = c*32+16*h2+dg+j)
        bf16x8 qh[2], ql[2];
        {
            const size_t qrow = ((size_t)h * SEQ + (size_t)qt * 64 + w * 16 + l15) * DK;
#pragma unroll
            for (int c = 0; c < 2; ++c) {
                union { ushort4 h4[2]; bf16x8 v; } uh, ul;
                uh.h4[0] = *reinterpret_cast<const ushort4*>(&Qhi[qrow + c * 32 + dg]);
                uh.h4[1] = *reinterpret_cast<const ushort4*>(&Qhi[qrow + c * 32 + 16 + dg]);
                ul.h4[0] = *reinterpret_cast<const ushort4*>(&Qlo[qrow + c * 32 + dg]);
                ul.h4[1] = *reinterpret_cast<const ushort4*>(&Qlo[qrow + c * 32 + 16 + dg]);
                qh[c] = uh.v; ql[c] = ul.v;
            }
        }

        f32x4 yacc[4];
#pragma unroll
        for (int dt = 0; dt < 4; ++dt) yacc[dt] = (f32x4){0.f, 0.f, 0.f, 0.f};
        float m_run = -1e30f, l_run = 0.0f;

        for (int kt = 0; kt <= qt; ++kt) {
            __syncthreads();
            // ---- stage K/V (hi,lo) 64x64 tiles ----
            {
                const int srow = t >> 3;
                const int scol = (t & 7) * 8;
#pragma unroll
                for (int u = 0; u < 2; ++u) {
                    const int row = u * 32 + srow;
                    const size_t gK = ((size_t)h * SEQ + (size_t)kt * 64 + row) * DK + scol;
                    const size_t gV = ((size_t)h * DK + row) * SEQ + (size_t)kt * 64 + scol;
                    union { u16x8 v; ushort4 q[2]; } a;
                    a.v = *reinterpret_cast<const u16x8*>(&Khi[gK]);
                    *reinterpret_cast<ushort4*>(&KsH[row][scol])     = a.q[0];
                    *reinterpret_cast<ushort4*>(&KsH[row][scol + 4]) = a.q[1];
                    a.v = *reinterpret_cast<const u16x8*>(&Klo[gK]);
                    *reinterpret_cast<ushort4*>(&KsL[row][scol])     = a.q[0];
                    *reinterpret_cast<ushort4*>(&KsL[row][scol + 4]) = a.q[1];
                    a.v = *reinterpret_cast<const u16x8*>(&Vhi[gV]);
                    *reinterpret_cast<ushort4*>(&VsH[row][scol])     = a.q[0];
                    *reinterpret_cast<ushort4*>(&VsH[row][scol + 4]) = a.q[1];
                    a.v = *reinterpret_cast<const u16x8*>(&Vlo[gV]);
                    *reinterpret_cast<ushort4*>(&VsL[row][scol])     = a.q[0];
                    *reinterpret_cast<ushort4*>(&VsL[row][scol + 4]) = a.q[1];
                }
            }
            __syncthreads();

            const bool diag = (kt == qt);

            // ---- S^T = K * Q^T (3-term hi/lo), per 16-key tile ----
            f32x4 st[4];
#pragma unroll
            for (int ktile = 0; ktile < 4; ++ktile) {
                if (diag && ktile > w) {   // fully-masked tile for this wave
                    st[ktile] = (f32x4){-1e30f, -1e30f, -1e30f, -1e30f};
                    continue;
                }
                f32x4 s = (f32x4){0.f, 0.f, 0.f, 0.f};
#pragma unroll
                for (int c = 0; c < 2; ++c) {
                    const int d0 = c * 32 + dg;
                    union { ushort4 h4[2]; bf16x8 v; } ah, al;
                    ah.h4[0] = *reinterpret_cast<const ushort4*>(&KsH[ktile * 16 + l15][d0]);
                    ah.h4[1] = *reinterpret_cast<const ushort4*>(&KsH[ktile * 16 + l15][d0 + 16]);
                    al.h4[0] = *reinterpret_cast<const ushort4*>(&KsL[ktile * 16 + l15][d0]);
                    al.h4[1] = *reinterpret_cast<const ushort4*>(&KsL[ktile * 16 + l15][d0 + 16]);
                    s = __builtin_amdgcn_mfma_f32_16x16x32_bf16(ah.v, qh[c], s, 0, 0, 0);
                    s = __builtin_amdgcn_mfma_f32_16x16x32_bf16(ah.v, ql[c], s, 0, 0, 0);
                    s = __builtin_amdgcn_mfma_f32_16x16x32_bf16(al.v, qh[c], s, 0, 0, 0);
                }
                st[ktile] = s;
            }

            if (diag) {   // causal mask on the diagonal tile
                const int qrel = w * 16 + l15;
#pragma unroll
                for (int ktile = 0; ktile < 4; ++ktile)
#pragma unroll
                    for (int r = 0; r < 4; ++r)
                        if (ktile * 16 + dg + r > qrel) st[ktile][r] = -1e30f;
            }

            // ---- online softmax (in-register; per-lane q = l15) ----
            float mx = m_run;
#pragma unroll
            for (int ktile = 0; ktile < 4; ++ktile)
#pragma unroll
                for (int r = 0; r < 4; ++r) mx = fmaxf(mx, st[ktile][r]);
            mx = fmaxf(mx, __shfl_xor(mx, 16));
            mx = fmaxf(mx, __shfl_xor(mx, 32));
            const float factor = __expf(m_run - mx);
            m_run = mx;

            float psum = 0.0f;
            unsigned short ph[4][4], pl[4][4];
#pragma unroll
            for (int ktile = 0; ktile < 4; ++ktile)
#pragma unroll
                for (int r = 0; r < 4; ++r) {
                    const float p = __expf(st[ktile][r] - mx);
                    psum += p;
                    const unsigned short hh = f2bf(p);
                    ph[ktile][r] = hh;
                    pl[ktile][r] = f2bf(p - bf2f(hh));
                }
            psum += __shfl_xor(psum, 16);
            psum += __shfl_xor(psum, 32);
            l_run = l_run * factor + psum;

            // rescale y: factor for q' = lg*4+r lives in lane q' (group 0)
#pragma unroll
            for (int r = 0; r < 4; ++r) {
                const float fr = __shfl(factor, (lg << 2) | r);
#pragma unroll
                for (int dt = 0; dt < 4; ++dt) yacc[dt][r] *= fr;
            }

            // pack P fragments (A-operand of PV): regs j<4 <- ktile 2c, j>=4 <- ktile 2c+1
            union { unsigned short a[8]; bf16x8 v; } pah[2], pal[2];
#pragma unroll
            for (int c = 0; c < 2; ++c)
#pragma unroll
                for (int j = 0; j < 4; ++j) {
                    pah[c].a[j]     = ph[2 * c][j];
                    pah[c].a[4 + j] = ph[2 * c + 1][j];
                    pal[c].a[j]     = pl[2 * c][j];
                    pal[c].a[4 + j] = pl[2 * c + 1][j];
                }

            // ---- y += P * V (3-term hi/lo) ----
            const int cmax = diag ? (w >> 1) : 1;
#pragma unroll
            for (int dt = 0; dt < 4; ++dt) {
                f32x4 acc = yacc[dt];
#pragma unroll
                for (int c = 0; c < 2; ++c) {
                    if (c > cmax) break;
                    const int k0 = c * 32 + dg;
                    union { ushort4 h4[2]; bf16x8 v; } vh, vl;
                    vh.h4[0] = *reinterpret_cast<const ushort4*>(&VsH[dt * 16 + l15][k0]);
                    vh.h4[1] = *reinterpret_cast<const ushort4*>(&VsH[dt * 16 + l15][k0 + 16]);
                    vl.h4[0] = *reinterpret_cast<const ushort4*>(&VsL[dt * 16 + l15][k0]);
                    vl.h4[1] = *reinterpret_cast<const ushort4*>(&VsL[dt * 16 + l15][k0 + 16]);
                    acc = __builtin_amdgcn_mfma_f32_16x16x32_bf16(pah[c].v, vh.v, acc, 0, 0, 0);
                    acc = __builtin_amdgcn_mfma_f32_16x16x32_bf16(pah[c].v, vl.v, acc, 0, 0, 0);
                    acc = __builtin_amdgcn_mfma_f32_16x16x32_bf16(pal[c].v, vh.v, acc, 0, 0, 0);
                }
                yacc[dt] = acc;
            }
        } // kt

        // ---- normalize + store: y row q' = qt*64 + w*16 + lg*4 + r ----
        const float inv = 1.0f / l_run;
#pragma unroll
        for (int r = 0; r < 4; ++r) {
            const float ir = __shfl(inv, (lg << 2) | r);
            float* yp = &Y[((size_t)qt * 64 + w * 16 + lg * 4 + r) * DM + h * DK];
#pragma unroll
            for (int dt = 0; dt < 4; ++dt) yp[dt * 16 + l15] = yacc[dt][r] * ir;
        }
    } // pass
}

// ---------------------------------------------------------------------------
extern "C" void kernel_launch(void* const* d_in, const int* in_sizes, int n_in,
                              void* d_out, int out_size, void* d_ws, size_t ws_size,
                              hipStream_t stream)
{
    const float* x    = (const float*)d_in[0];
    const float* Wq   = (const float*)d_in[1];
    const float* Wk   = (const float*)d_in[2];
    const float* Wv   = (const float*)d_in[3];
    const float* Wo   = (const float*)d_in[4];
    const float* cosT = (const float*)d_in[5];
    const float* sinT = (const float*)d_in[6];
    const int*   pos  = (const int*)d_in[7];
    float* out = (float*)d_out;

    // Workspace (64 MB): 6 bf16 arrays of SEQ*DM (8MB each) + fp32 y (16MB)
    const size_t E = (size_t)SEQ * DM;
    unsigned short* qhi = (unsigned short*)d_ws;
    unsigned short* qlo = qhi + E;
    unsigned short* khi = qlo + E;
    unsigned short* klo = khi + E;
    unsigned short* vhi = klo + E;
    unsigned short* vlo = vhi + E;
    float* y = (float*)(vlo + E);

    dim3 gg(DM / 128, SEQ / 128), bb(256);
    gemm_xwt<2><<<gg, bb, 0, stream>>>(x, Wq, qhi, qlo, cosT, sinT, pos, SEQ, DM, DM);
    gemm_xwt<3><<<gg, bb, 0, stream>>>(x, Wk, khi, klo, cosT, sinT, pos, SEQ, DM, DM);
    gemm_xwt<1><<<gg, bb, 0, stream>>>(x, Wv, vhi, vlo, cosT, sinT, pos, SEQ, DM, DM);
    attn_mfma<<<dim3(512), bb, 0, stream>>>(qhi, qlo, khi, klo, vhi, vlo, y);
    gemm_xwt<0><<<gg, bb, 0, stream>>>(y, Wo, out, nullptr, cosT, sinT, pos, SEQ, DM, DM);
}

// Round 3
// 287.863 us; speedup vs baseline: 7.1828x; 2.3902x over previous
//
#include <hip/hip_runtime.h>
#include <math.h>

#define SEQ 4096
#define DM  1024
#define NH  16
#define DK  64

typedef __attribute__((ext_vector_type(4))) float f32x4;
typedef __attribute__((ext_vector_type(8))) short bf16x8;
typedef __attribute__((ext_vector_type(8))) unsigned short u16x8;

__device__ __forceinline__ unsigned short bf_hi(float f) {
    return (unsigned short)(__float_as_uint(f) >> 16);   // trunc split: lo absorbs the error
}
__device__ __forceinline__ float bf_f(unsigned short s) {
    return __uint_as_float(((unsigned)s) << 16);
}

union FragU { u16x8 u; bf16x8 b; ushort4 q[2]; };

// ---------------------------------------------------------------------------
// MFMA GEMM, 3-term bf16 hi/lo emulation, fp32 in. C = A * W^T.
// A: [M=4096][K=1024] fp32. W: [N][K] fp32 row-major.
// MODE 4: fused QKV (N=3072; wt=bx/16 selects Wq/Wk/Wv + epilogue:
//         Q: RoPE + 1/8 scale + [head][seq][64] hi/lo store
//         K: RoPE +           [head][seq][64] hi/lo store
//         V: transposed [head*64+d][seq] hi/lo store)
// MODE 0: Wo -> fp32 out [4096][1024]
// Tile 128x64, BK=32, 4 waves (64x32 each, acc[4][2] of 16x16 frags).
// LDS k-permuted (k=16h+4g+j -> col 8g+4h+j, +32 for lo) so each fragment
// is one contiguous ds_read_b128. Pitch 72 shorts = 144B (16B-aligned,
// frag reads bank-uniform). Schedule: write(t); bar; load(t+1); mfma(t); bar.
// ---------------------------------------------------------------------------
template<int MODE>
__global__ __launch_bounds__(256)
void gemm_mfma(const float* __restrict__ A,
               const float* __restrict__ W0, const float* __restrict__ W1,
               const float* __restrict__ W2,
               unsigned short* __restrict__ OQh, unsigned short* __restrict__ OQl,
               unsigned short* __restrict__ OKh, unsigned short* __restrict__ OKl,
               unsigned short* __restrict__ OVh, unsigned short* __restrict__ OVl,
               float* __restrict__ Ofp,
               const float* __restrict__ cosT, const float* __restrict__ sinT,
               const int* __restrict__ positions)
{
    constexpr int NT = (MODE == 4) ? 48 : 16;
    __shared__ unsigned short As[128][72];
    __shared__ unsigned short Bs[64][72];

    const int t   = threadIdx.x;
    const int bid = blockIdx.x;
    const int q8  = (32 * NT) >> 3;                 // blocks per XCD
    const int swz = (bid & 7) * q8 + (bid >> 3);    // XCD-aware swizzle (nwg%8==0)
    const int by  = swz / NT;
    const int bxf = swz % NT;
    const int wt  = (MODE == 4) ? (bxf >> 4) : 0;
    const int bx  = (MODE == 4) ? (bxf & 15) : bxf;
    const int m0  = by * 128;
    const int n0  = bx * 64;
    const float* W = (MODE == 4) ? (wt == 0 ? W0 : (wt == 1 ? W1 : W2)) : W0;

    const int lane = t & 63;
    const int w    = t >> 6;
    const int wr   = w >> 1, wc = w & 1;
    const int l15  = lane & 15;
    const int lg   = lane >> 4;

    // staging assignment: A row=t>>1 (16 floats, k-half ah); B row=t>>2 (8 floats, quarter bq)
    const int ar = t >> 1, ah = t & 1;
    const int br = t >> 2, bq = t & 3;
    const float* Ap = &A[(size_t)(m0 + ar) * DM + ah * 16];
    const float* Wp = &W[(size_t)(n0 + br) * DM + bq * 8];

    f32x4 acc[4][2];
#pragma unroll
    for (int mi = 0; mi < 4; ++mi)
#pragma unroll
        for (int ni = 0; ni < 2; ++ni) acc[mi][ni] = (f32x4){0.f, 0.f, 0.f, 0.f};

    float4 pa[4], pb[2];
#pragma unroll
    for (int u = 0; u < 4; ++u) pa[u] = *reinterpret_cast<const float4*>(Ap + u * 4);
    pb[0] = *reinterpret_cast<const float4*>(Wp);
    pb[1] = *reinterpret_cast<const float4*>(Wp + 4);

    for (int kt = 0; kt < 32; ++kt) {
        // ---- split + k-permuted LDS write of tile kt ----
#pragma unroll
        for (int g = 0; g < 4; ++g) {
            ushort4 hv, lv;
            const float4 v = pa[g];
            const float vf[4] = {v.x, v.y, v.z, v.w};
            unsigned short* hp = (unsigned short*)&hv;
            unsigned short* lp = (unsigned short*)&lv;
#pragma unroll
            for (int jj = 0; jj < 4; ++jj) {
                const unsigned short h = bf_hi(vf[jj]);
                hp[jj] = h; lp[jj] = bf_hi(vf[jj] - bf_f(h));
            }
            *reinterpret_cast<ushort4*>(&As[ar][8 * g + 4 * ah])      = hv;
            *reinterpret_cast<ushort4*>(&As[ar][32 + 8 * g + 4 * ah]) = lv;
        }
#pragma unroll
        for (int u = 0; u < 2; ++u) {
            const int g = 2 * (bq & 1) + u, h2 = bq >> 1;
            ushort4 hv, lv;
            const float4 v = pb[u];
            const float vf[4] = {v.x, v.y, v.z, v.w};
            unsigned short* hp = (unsigned short*)&hv;
            unsigned short* lp = (unsigned short*)&lv;
#pragma unroll
            for (int jj = 0; jj < 4; ++jj) {
                const unsigned short h = bf_hi(vf[jj]);
                hp[jj] = h; lp[jj] = bf_hi(vf[jj] - bf_f(h));
            }
            *reinterpret_cast<ushort4*>(&Bs[br][8 * g + 4 * h2])      = hv;
            *reinterpret_cast<ushort4*>(&Bs[br][32 + 8 * g + 4 * h2]) = lv;
        }
        __syncthreads();

        // ---- issue next tile's global loads (latency hides under MFMA) ----
        if (kt < 31) {
            const float* Apn = Ap + (kt + 1) * 32;
            const float* Wpn = Wp + (kt + 1) * 32;
#pragma unroll
            for (int u = 0; u < 4; ++u) pa[u] = *reinterpret_cast<const float4*>(Apn + u * 4);
            pb[0] = *reinterpret_cast<const float4*>(Wpn);
            pb[1] = *reinterpret_cast<const float4*>(Wpn + 4);
        }

        // ---- fragments + MFMA ----
        FragU a_h[4], a_l[4], b_h[2], b_l[2];
#pragma unroll
        for (int mi = 0; mi < 4; ++mi) {
            const int row = wr * 64 + mi * 16 + l15;
            a_h[mi].u = *reinterpret_cast<const u16x8*>(&As[row][8 * lg]);
            a_l[mi].u = *reinterpret_cast<const u16x8*>(&As[row][32 + 8 * lg]);
        }
#pragma unroll
        for (int ni = 0; ni < 2; ++ni) {
            const int row = wc * 32 + ni * 16 + l15;
            b_h[ni].u = *reinterpret_cast<const u16x8*>(&Bs[row][8 * lg]);
            b_l[ni].u = *reinterpret_cast<const u16x8*>(&Bs[row][32 + 8 * lg]);
        }
#pragma unroll
        for (int mi = 0; mi < 4; ++mi)
#pragma unroll
            for (int ni = 0; ni < 2; ++ni) {
                f32x4 c = acc[mi][ni];
                c = __builtin_amdgcn_mfma_f32_16x16x32_bf16(a_h[mi].b, b_h[ni].b, c, 0, 0, 0);
                c = __builtin_amdgcn_mfma_f32_16x16x32_bf16(a_h[mi].b, b_l[ni].b, c, 0, 0, 0);
                c = __builtin_amdgcn_mfma_f32_16x16x32_bf16(a_l[mi].b, b_h[ni].b, c, 0, 0, 0);
                acc[mi][ni] = c;
            }
        __syncthreads();
    }

    // ---- epilogue.  C frag layout: row = lg*4 + r, col = l15 ----
    if (MODE == 0) {
#pragma unroll
        for (int mi = 0; mi < 4; ++mi)
#pragma unroll
            for (int ni = 0; ni < 2; ++ni)
#pragma unroll
                for (int r = 0; r < 4; ++r) {
                    const int m  = m0 + wr * 64 + mi * 16 + lg * 4 + r;
                    const int ng = n0 + wc * 32 + ni * 16 + l15;
                    Ofp[(size_t)m * DM + ng] = acc[mi][ni][r];
                }
    } else if (wt == 2) {
        // V: transposed store Vt[n][seq], n = head*64+d = n0 + n_local
#pragma unroll
        for (int mi = 0; mi < 4; ++mi)
#pragma unroll
            for (int ni = 0; ni < 2; ++ni) {
                ushort4 hv, lv;
                unsigned short* hp = (unsigned short*)&hv;
                unsigned short* lp = (unsigned short*)&lv;
#pragma unroll
                for (int r = 0; r < 4; ++r) {
                    const float f = acc[mi][ni][r];
                    const unsigned short h = bf_hi(f);
                    hp[r] = h; lp[r] = bf_hi(f - bf_f(h));
                }
                const int ng = n0 + wc * 32 + ni * 16 + l15;
                const size_t off = (size_t)ng * SEQ + m0 + wr * 64 + mi * 16 + lg * 4;
                *reinterpret_cast<ushort4*>(&OVh[off]) = hv;
                *reinterpret_cast<ushort4*>(&OVl[off]) = lv;
            }
    } else {
        // Q/K: RoPE (+1/8 for Q), head-split hi/lo store
        unsigned short* Oh = (wt == 0) ? OQh : OKh;
        unsigned short* Ol = (wt == 0) ? OQl : OKl;
        const int head = bx;
#pragma unroll
        for (int mi = 0; mi < 4; ++mi)
#pragma unroll
            for (int r = 0; r < 4; ++r) {
                const int m   = m0 + wr * 64 + mi * 16 + lg * 4 + r;
                const int pos = positions[m];
#pragma unroll
                for (int ni = 0; ni < 2; ++ni) {
                    float val = acc[mi][ni][r];
                    const int d = wc * 32 + ni * 16 + l15;
                    const float other = __shfl_xor(val, 1);
                    const float cc = cosT[pos * (DK / 2) + (d >> 1)];
                    const float ss = sinT[pos * (DK / 2) + (d >> 1)];
                    val = (d & 1) ? fmaf(other, ss, val * cc)
                                  : fmaf(other, -ss, val * cc);
                    if (wt == 0) val *= 0.125f;
                    const unsigned short h = bf_hi(val);
                    const unsigned short l = bf_hi(val - bf_f(h));
                    const size_t off = ((size_t)head * SEQ + m) * DK + d;
                    Oh[off] = h; Ol[off] = l;
                }
            }
    }
}

// ---------------------------------------------------------------------------
// MFMA flash attention (round-2 validated structure) + trunc splits,
// defer-max (THR=8), s_setprio around MFMA clusters.
// ---------------------------------------------------------------------------
__global__ __launch_bounds__(256)
void attn_mfma(const unsigned short* __restrict__ Qhi, const unsigned short* __restrict__ Qlo,
               const unsigned short* __restrict__ Khi, const unsigned short* __restrict__ Klo,
               const unsigned short* __restrict__ Vhi, const unsigned short* __restrict__ Vlo,
               float* __restrict__ Y)
{
    __shared__ unsigned short KsH[64][68], KsL[64][68];
    __shared__ unsigned short VsH[64][68], VsL[64][68];

    const int t    = threadIdx.x;
    const int lane = t & 63;
    const int w    = t >> 6;
    const int bid  = blockIdx.x;
    const int h    = 2 * (bid & 7) + ((bid >> 3) >> 5);
    const int bx   = (bid >> 3) & 31;

    const int l15 = lane & 15;
    const int lg  = lane >> 4;
    const int dg  = lg * 4;

#pragma unroll 1
    for (int pass = 0; pass < 2; ++pass) {
        const int qt = pass ? (63 - bx) : bx;

        bf16x8 qh[2], ql[2];
        {
            const size_t qrow = ((size_t)h * SEQ + (size_t)qt * 64 + w * 16 + l15) * DK;
#pragma unroll
            for (int c = 0; c < 2; ++c) {
                FragU uh, ul;
                uh.q[0] = *reinterpret_cast<const ushort4*>(&Qhi[qrow + c * 32 + dg]);
                uh.q[1] = *reinterpret_cast<const ushort4*>(&Qhi[qrow + c * 32 + 16 + dg]);
                ul.q[0] = *reinterpret_cast<const ushort4*>(&Qlo[qrow + c * 32 + dg]);
                ul.q[1] = *reinterpret_cast<const ushort4*>(&Qlo[qrow + c * 32 + 16 + dg]);
                qh[c] = uh.b; ql[c] = ul.b;
            }
        }

        f32x4 yacc[4];
#pragma unroll
        for (int dt = 0; dt < 4; ++dt) yacc[dt] = (f32x4){0.f, 0.f, 0.f, 0.f};
        float m_run = -1e30f, l_run = 0.0f;

        for (int kt = 0; kt <= qt; ++kt) {
            __syncthreads();
            {
                const int srow = t >> 3;
                const int scol = (t & 7) * 8;
#pragma unroll
                for (int u = 0; u < 2; ++u) {
                    const int row = u * 32 + srow;
                    const size_t gK = ((size_t)h * SEQ + (size_t)kt * 64 + row) * DK + scol;
                    const size_t gV = ((size_t)h * DK + row) * SEQ + (size_t)kt * 64 + scol;
                    FragU a;
                    a.u = *reinterpret_cast<const u16x8*>(&Khi[gK]);
                    *reinterpret_cast<ushort4*>(&KsH[row][scol])     = a.q[0];
                    *reinterpret_cast<ushort4*>(&KsH[row][scol + 4]) = a.q[1];
                    a.u = *reinterpret_cast<const u16x8*>(&Klo[gK]);
                    *reinterpret_cast<ushort4*>(&KsL[row][scol])     = a.q[0];
                    *reinterpret_cast<ushort4*>(&KsL[row][scol + 4]) = a.q[1];
                    a.u = *reinterpret_cast<const u16x8*>(&Vhi[gV]);
                    *reinterpret_cast<ushort4*>(&VsH[row][scol])     = a.q[0];
                    *reinterpret_cast<ushort4*>(&VsH[row][scol + 4]) = a.q[1];
                    a.u = *reinterpret_cast<const u16x8*>(&Vlo[gV]);
                    *reinterpret_cast<ushort4*>(&VsL[row][scol])     = a.q[0];
                    *reinterpret_cast<ushort4*>(&VsL[row][scol + 4]) = a.q[1];
                }
            }
            __syncthreads();

            const bool diag = (kt == qt);

            f32x4 st[4];
            __builtin_amdgcn_s_setprio(1);
#pragma unroll
            for (int ktile = 0; ktile < 4; ++ktile) {
                if (diag && ktile > w) {
                    st[ktile] = (f32x4){-1e30f, -1e30f, -1e30f, -1e30f};
                    continue;
                }
                f32x4 s = (f32x4){0.f, 0.f, 0.f, 0.f};
#pragma unroll
                for (int c = 0; c < 2; ++c) {
                    const int d0 = c * 32 + dg;
                    FragU ahf, alf;
                    ahf.q[0] = *reinterpret_cast<const ushort4*>(&KsH[ktile * 16 + l15][d0]);
                    ahf.q[1] = *reinterpret_cast<const ushort4*>(&KsH[ktile * 16 + l15][d0 + 16]);
                    alf.q[0] = *reinterpret_cast<const ushort4*>(&KsL[ktile * 16 + l15][d0]);
                    alf.q[1] = *reinterpret_cast<const ushort4*>(&KsL[ktile * 16 + l15][d0 + 16]);
                    s = __builtin_amdgcn_mfma_f32_16x16x32_bf16(ahf.b, qh[c], s, 0, 0, 0);
                    s = __builtin_amdgcn_mfma_f32_16x16x32_bf16(ahf.b, ql[c], s, 0, 0, 0);
                    s = __builtin_amdgcn_mfma_f32_16x16x32_bf16(alf.b, qh[c], s, 0, 0, 0);
                }
                st[ktile] = s;
            }
            __builtin_amdgcn_s_setprio(0);

            if (diag) {
                const int qrel = w * 16 + l15;
#pragma unroll
                for (int ktile = 0; ktile < 4; ++ktile)
#pragma unroll
                    for (int r = 0; r < 4; ++r)
                        if (ktile * 16 + dg + r > qrel) st[ktile][r] = -1e30f;
            }

            // ---- online softmax with defer-max ----
            float rowmax = -1e30f;
#pragma unroll
            for (int ktile = 0; ktile < 4; ++ktile)
#pragma unroll
                for (int r = 0; r < 4; ++r) rowmax = fmaxf(rowmax, st[ktile][r]);
            rowmax = fmaxf(rowmax, __shfl_xor(rowmax, 16));
            rowmax = fmaxf(rowmax, __shfl_xor(rowmax, 32));
            if (!__all(rowmax <= m_run + 8.0f)) {
                const float mnew   = fmaxf(m_run, rowmax);
                const float factor = __expf(m_run - mnew);
                l_run *= factor;
#pragma unroll
                for (int r = 0; r < 4; ++r) {
                    const float fr = __shfl(factor, (lg << 2) | r);
#pragma unroll
                    for (int dt = 0; dt < 4; ++dt) yacc[dt][r] *= fr;
                }
                m_run = mnew;
            }

            float psum = 0.0f;
            unsigned short ph[4][4], pl[4][4];
#pragma unroll
            for (int ktile = 0; ktile < 4; ++ktile)
#pragma unroll
                for (int r = 0; r < 4; ++r) {
                    const float p = __expf(st[ktile][r] - m_run);
                    psum += p;
                    const unsigned short hh = bf_hi(p);
                    ph[ktile][r] = hh;
                    pl[ktile][r] = bf_hi(p - bf_f(hh));
                }
            psum += __shfl_xor(psum, 16);
            psum += __shfl_xor(psum, 32);
            l_run += psum;

            union { unsigned short a[8]; bf16x8 v; } pah[2], pal[2];
#pragma unroll
            for (int c = 0; c < 2; ++c)
#pragma unroll
                for (int j = 0; j < 4; ++j) {
                    pah[c].a[j]     = ph[2 * c][j];
                    pah[c].a[4 + j] = ph[2 * c + 1][j];
                    pal[c].a[j]     = pl[2 * c][j];
                    pal[c].a[4 + j] = pl[2 * c + 1][j];
                }

            const int cmax = diag ? (w >> 1) : 1;
            __builtin_amdgcn_s_setprio(1);
#pragma unroll
            for (int dt = 0; dt < 4; ++dt) {
                f32x4 acc = yacc[dt];
#pragma unroll
                for (int c = 0; c < 2; ++c) {
                    if (c > cmax) break;
                    const int k0 = c * 32 + dg;
                    FragU vh, vl;
                    vh.q[0] = *reinterpret_cast<const ushort4*>(&VsH[dt * 16 + l15][k0]);
                    vh.q[1] = *reinterpret_cast<const ushort4*>(&VsH[dt * 16 + l15][k0 + 16]);
                    vl.q[0] = *reinterpret_cast<const ushort4*>(&VsL[dt * 16 + l15][k0]);
                    vl.q[1] = *reinterpret_cast<const ushort4*>(&VsL[dt * 16 + l15][k0 + 16]);
                    acc = __builtin_amdgcn_mfma_f32_16x16x32_bf16(pah[c].v, vh.b, acc, 0, 0, 0);
                    acc = __builtin_amdgcn_mfma_f32_16x16x32_bf16(pah[c].v, vl.b, acc, 0, 0, 0);
                    acc = __builtin_amdgcn_mfma_f32_16x16x32_bf16(pal[c].v, vh.b, acc, 0, 0, 0);
                }
                yacc[dt] = acc;
            }
            __builtin_amdgcn_s_setprio(0);
        } // kt

        const float inv = 1.0f / l_run;
#pragma unroll
        for (int r = 0; r < 4; ++r) {
            const float ir = __shfl(inv, (lg << 2) | r);
            float* yp = &Y[((size_t)qt * 64 + w * 16 + lg * 4 + r) * DM + h * DK];
#pragma unroll
            for (int dt = 0; dt < 4; ++dt) yp[dt * 16 + l15] = yacc[dt][r] * ir;
        }
    } // pass
}

// ---------------------------------------------------------------------------
extern "C" void kernel_launch(void* const* d_in, const int* in_sizes, int n_in,
                              void* d_out, int out_size, void* d_ws, size_t ws_size,
                              hipStream_t stream)
{
    const float* x    = (const float*)d_in[0];
    const float* Wq   = (const float*)d_in[1];
    const float* Wk   = (const float*)d_in[2];
    const float* Wv   = (const float*)d_in[3];
    const float* Wo   = (const float*)d_in[4];
    const float* cosT = (const float*)d_in[5];
    const float* sinT = (const float*)d_in[6];
    const int*   pos  = (const int*)d_in[7];
    float* out = (float*)d_out;

    // Workspace (64 MB): q/k/v hi+lo bf16 (6 x 8MB) + y fp32 (16MB)
    const size_t E = (size_t)SEQ * DM;
    unsigned short* qh = (unsigned short*)d_ws;
    unsigned short* ql = qh + E;
    unsigned short* kh = ql + E;
    unsigned short* kl = kh + E;
    unsigned short* vh = kl + E;
    unsigned short* vl = vh + E;
    float* y = (float*)(vl + E);

    gemm_mfma<4><<<dim3(32 * 48), dim3(256), 0, stream>>>(
        x, Wq, Wk, Wv, qh, ql, kh, kl, vh, vl, nullptr, cosT, sinT, pos);
    attn_mfma<<<dim3(512), dim3(256), 0, stream>>>(qh, ql, kh, kl, vh, vl, y);
    gemm_mfma<0><<<dim3(32 * 16), dim3(256), 0, stream>>>(
        y, Wo, nullptr, nullptr, nullptr, nullptr, nullptr, nullptr, nullptr, nullptr,
        out, cosT, sinT, pos);
}

// Round 4
// 258.930 us; speedup vs baseline: 7.9854x; 1.1117x over previous
//
#include <hip/hip_runtime.h>
#include <math.h>

#define SEQ 4096
#define DM  1024
#define NH  16
#define DK  64

typedef __attribute__((ext_vector_type(4))) float f32x4;
typedef __attribute__((ext_vector_type(8))) short bf16x8;
typedef __attribute__((ext_vector_type(8))) unsigned short u16x8;

union FragU { u16x8 u; bf16x8 b; ushort4 q[2]; unsigned w[4]; };

__device__ __forceinline__ unsigned cvtpk(float a, float b) {
    unsigned r; asm("v_cvt_pk_bf16_f32 %0, %1, %2" : "=v"(r) : "v"(a), "v"(b)); return r;
}
__device__ __forceinline__ float fexp2(float x) {
    float r; asm("v_exp_f32 %0, %1" : "=v"(r) : "v"(x)); return r;
}
__device__ __forceinline__ void split4(float4 v, ushort4& hv, ushort4& lv) {
    union { ushort4 q; unsigned w[2]; } H, L;
    H.w[0] = cvtpk(v.x, v.y); H.w[1] = cvtpk(v.z, v.w);
    const float rx = v.x - __uint_as_float(H.w[0] << 16);
    const float ry = v.y - __uint_as_float(H.w[0] & 0xffff0000u);
    const float rz = v.z - __uint_as_float(H.w[1] << 16);
    const float rw = v.w - __uint_as_float(H.w[1] & 0xffff0000u);
    L.w[0] = cvtpk(rx, ry); L.w[1] = cvtpk(rz, rw);
    hv = H.q; lv = L.q;
}
__device__ __forceinline__ void split1(float f, unsigned short& h, unsigned short& l) {
    const unsigned hw = cvtpk(f, f) & 0xffffu;
    h = (unsigned short)hw;
    const float r = f - __uint_as_float(hw << 16);
    l = (unsigned short)(__float_as_uint(r) >> 16);
}

// ---------------------------------------------------------------------------
// MFMA GEMM, 3-term bf16 hi/lo emulation. C = A * W^T.
// MODE 4: fused QKV. A = x fp32 [4096][1024]; W0/1/2 = Wq/Wk/Wv.
//   epilogues: Q RoPE + 0.125*log2e scale -> [head][seq][64] hi/lo
//              K RoPE -> [head][seq][64] hi/lo; V -> transposed [h*64+d][seq]
// MODE 0: Wo. A = pre-split y (Ahi/Alo bf16) -> fp32 out [4096][1024].
// Tile 128x128, BK=32, 4 waves (64x64 each, acc[4][4]).
// LDS k-permuted (k=16h+4g+j -> col 8g+4h+j; +32 for lo), pitch 76.
// ---------------------------------------------------------------------------
template<int MODE>
__global__ __launch_bounds__(256, 2)
void gemm_mfma(const float* __restrict__ Af,
               const unsigned short* __restrict__ Ahi, const unsigned short* __restrict__ Alo,
               const float* __restrict__ W0, const float* __restrict__ W1,
               const float* __restrict__ W2,
               unsigned short* __restrict__ OQh, unsigned short* __restrict__ OQl,
               unsigned short* __restrict__ OKh, unsigned short* __restrict__ OKl,
               unsigned short* __restrict__ OVh, unsigned short* __restrict__ OVl,
               float* __restrict__ Ofp,
               const float* __restrict__ cosT, const float* __restrict__ sinT,
               const int* __restrict__ positions)
{
    constexpr int NT = (MODE == 4) ? 24 : 8;   // n-tiles of 128
    __shared__ unsigned short As[128][76];
    __shared__ unsigned short Bs[128][76];

    const int t   = threadIdx.x;
    const int bid = blockIdx.x;
    const int qpx = (32 * NT) >> 3;                 // blocks per XCD
    const int swz = (bid & 7) * qpx + (bid >> 3);   // XCD swizzle (nwg%8==0)
    const int by  = swz / NT;
    const int bxf = swz % NT;
    const int wt  = (MODE == 4) ? (bxf >> 3) : 0;
    const int bx  = (MODE == 4) ? (bxf & 7) : bxf;
    const int m0  = by * 128;
    const float* W = (MODE == 4) ? (wt == 0 ? W0 : (wt == 1 ? W1 : W2)) : W0;

    const int lane = t & 63, w = t >> 6;
    const int wr = w >> 1, wc = w & 1;
    const int l15 = lane & 15, lg = lane >> 4;

    // staging: each thread handles row ar, k-half ah (16 elems) for A and B
    const int ar = t >> 1, ah = t & 1;
    const float* Ap = (MODE == 4) ? &Af[(size_t)(m0 + ar) * DM + ah * 16] : nullptr;
    const unsigned short* Aph = (MODE == 0) ? &Ahi[(size_t)(m0 + ar) * DM + ah * 16] : nullptr;
    const unsigned short* Apl = (MODE == 0) ? &Alo[(size_t)(m0 + ar) * DM + ah * 16] : nullptr;
    const float* Wp = &W[(size_t)(bx * 128 + ar) * DM + ah * 16];

    f32x4 acc[4][4];
#pragma unroll
    for (int mi = 0; mi < 4; ++mi)
#pragma unroll
        for (int ni = 0; ni < 4; ++ni) acc[mi][ni] = (f32x4){0.f, 0.f, 0.f, 0.f};

    float4 pa[4], pb[4];
    u16x8 pah[2], pal[2];
    if constexpr (MODE == 4) {
#pragma unroll
        for (int g = 0; g < 4; ++g) pa[g] = *reinterpret_cast<const float4*>(Ap + g * 4);
    } else {
        pah[0] = *reinterpret_cast<const u16x8*>(Aph);
        pah[1] = *reinterpret_cast<const u16x8*>(Aph + 8);
        pal[0] = *reinterpret_cast<const u16x8*>(Apl);
        pal[1] = *reinterpret_cast<const u16x8*>(Apl + 8);
    }
#pragma unroll
    for (int g = 0; g < 4; ++g) pb[g] = *reinterpret_cast<const float4*>(Wp + g * 4);

    for (int kt = 0; kt < 32; ++kt) {
        // ---- split + permuted LDS write ----
        if constexpr (MODE == 4) {
#pragma unroll
            for (int g = 0; g < 4; ++g) {
                ushort4 hv, lv;
                split4(pa[g], hv, lv);
                *reinterpret_cast<ushort4*>(&As[ar][8 * g + 4 * ah])      = hv;
                *reinterpret_cast<ushort4*>(&As[ar][32 + 8 * g + 4 * ah]) = lv;
            }
        } else {
            FragU h0, h1, l0, l1;
            h0.u = pah[0]; h1.u = pah[1]; l0.u = pal[0]; l1.u = pal[1];
            *reinterpret_cast<ushort4*>(&As[ar][0  + 4 * ah]) = h0.q[0];
            *reinterpret_cast<ushort4*>(&As[ar][8  + 4 * ah]) = h0.q[1];
            *reinterpret_cast<ushort4*>(&As[ar][16 + 4 * ah]) = h1.q[0];
            *reinterpret_cast<ushort4*>(&As[ar][24 + 4 * ah]) = h1.q[1];
            *reinterpret_cast<ushort4*>(&As[ar][32 + 4 * ah]) = l0.q[0];
            *reinterpret_cast<ushort4*>(&As[ar][40 + 4 * ah]) = l0.q[1];
            *reinterpret_cast<ushort4*>(&As[ar][48 + 4 * ah]) = l1.q[0];
            *reinterpret_cast<ushort4*>(&As[ar][56 + 4 * ah]) = l1.q[1];
        }
#pragma unroll
        for (int g = 0; g < 4; ++g) {
            ushort4 hv, lv;
            split4(pb[g], hv, lv);
            *reinterpret_cast<ushort4*>(&Bs[ar][8 * g + 4 * ah])      = hv;
            *reinterpret_cast<ushort4*>(&Bs[ar][32 + 8 * g + 4 * ah]) = lv;
        }
        __syncthreads();

        // ---- prefetch next k-tile ----
        if (kt < 31) {
            const int ko = (kt + 1) * 32;
            if constexpr (MODE == 4) {
#pragma unroll
                for (int g = 0; g < 4; ++g)
                    pa[g] = *reinterpret_cast<const float4*>(Ap + ko + g * 4);
            } else {
                pah[0] = *reinterpret_cast<const u16x8*>(Aph + ko);
                pah[1] = *reinterpret_cast<const u16x8*>(Aph + ko + 8);
                pal[0] = *reinterpret_cast<const u16x8*>(Apl + ko);
                pal[1] = *reinterpret_cast<const u16x8*>(Apl + ko + 8);
            }
#pragma unroll
            for (int g = 0; g < 4; ++g)
                pb[g] = *reinterpret_cast<const float4*>(Wp + ko + g * 4);
        }

        // ---- fragments + MFMA ----
        FragU b_h[4], b_l[4];
#pragma unroll
        for (int ni = 0; ni < 4; ++ni) {
            const int row = wc * 64 + ni * 16 + l15;
            b_h[ni].u = *reinterpret_cast<const u16x8*>(&Bs[row][8 * lg]);
            b_l[ni].u = *reinterpret_cast<const u16x8*>(&Bs[row][32 + 8 * lg]);
        }
#pragma unroll
        for (int mi = 0; mi < 4; ++mi) {
            FragU a_h, a_l;
            const int row = wr * 64 + mi * 16 + l15;
            a_h.u = *reinterpret_cast<const u16x8*>(&As[row][8 * lg]);
            a_l.u = *reinterpret_cast<const u16x8*>(&As[row][32 + 8 * lg]);
#pragma unroll
            for (int ni = 0; ni < 4; ++ni) {
                f32x4 c = acc[mi][ni];
                c = __builtin_amdgcn_mfma_f32_16x16x32_bf16(a_h.b, b_h[ni].b, c, 0, 0, 0);
                c = __builtin_amdgcn_mfma_f32_16x16x32_bf16(a_h.b, b_l[ni].b, c, 0, 0, 0);
                c = __builtin_amdgcn_mfma_f32_16x16x32_bf16(a_l.b, b_h[ni].b, c, 0, 0, 0);
                acc[mi][ni] = c;
            }
        }
        __syncthreads();
    }

    // ---- epilogue.  C frag: row = lg*4+r, col = l15 ----
    if constexpr (MODE == 0) {
#pragma unroll
        for (int mi = 0; mi < 4; ++mi)
#pragma unroll
            for (int ni = 0; ni < 4; ++ni)
#pragma unroll
                for (int r = 0; r < 4; ++r) {
                    const int m = m0 + wr * 64 + mi * 16 + lg * 4 + r;
                    const int n = bx * 128 + wc * 64 + ni * 16 + l15;
                    Ofp[(size_t)m * DM + n] = acc[mi][ni][r];
                }
    } else if (wt == 2) {
        // V transposed: rows n = head*64+d
#pragma unroll
        for (int mi = 0; mi < 4; ++mi)
#pragma unroll
            for (int ni = 0; ni < 4; ++ni) {
                ushort4 hv, lv;
                unsigned short* hp = (unsigned short*)&hv;
                unsigned short* lp = (unsigned short*)&lv;
#pragma unroll
                for (int r = 0; r < 4; ++r) split1(acc[mi][ni][r], hp[r], lp[r]);
                const int vrow = bx * 128 + wc * 64 + ni * 16 + l15;
                const size_t off = (size_t)vrow * SEQ + m0 + wr * 64 + mi * 16 + lg * 4;
                *reinterpret_cast<ushort4*>(&OVh[off]) = hv;
                *reinterpret_cast<ushort4*>(&OVl[off]) = lv;
            }
    } else {
        unsigned short* Oh = (wt == 0) ? OQh : OKh;
        unsigned short* Ol = (wt == 0) ? OQl : OKl;
        const int head = bx * 2 + wc;
        const float qsc = 0.1803368801f;   // 0.125 * log2(e)
#pragma unroll
        for (int mi = 0; mi < 4; ++mi)
#pragma unroll
            for (int r = 0; r < 4; ++r) {
                const int m   = m0 + wr * 64 + mi * 16 + lg * 4 + r;
                const int pos = positions[m];
#pragma unroll
                for (int ni = 0; ni < 4; ++ni) {
                    float val = acc[mi][ni][r];
                    const int d = ni * 16 + l15;
                    const float other = __shfl_xor(val, 1);
                    const float cc = cosT[pos * 32 + ni * 8 + (l15 >> 1)];
                    const float ss = sinT[pos * 32 + ni * 8 + (l15 >> 1)];
                    val = (d & 1) ? fmaf(other, ss, val * cc)
                                  : fmaf(other, -ss, val * cc);
                    if (wt == 0) val *= qsc;
                    unsigned short hh, ll;
                    split1(val, hh, ll);
                    const size_t off = ((size_t)head * SEQ + m) * DK + d;
                    Oh[off] = hh; Ol[off] = ll;
                }
            }
    }
}

// ---------------------------------------------------------------------------
// MFMA flash attention. QBLK=128 (4 waves x 32 rows = 2 frags each), KV tile 64.
// Q pre-scaled by 0.125*log2e -> exp2 softmax. QK 3-term; PV 2-term with
// cvt_pk RNE P. K/V LDS k-permuted (b128 frags), pitch 72, reg-prefetch (T14).
// Pairing (p, 31-p): uniform 68 iters. Y out bf16 hi/lo [4096][1024].
// ---------------------------------------------------------------------------
__global__ __launch_bounds__(256, 1)
void attn_mfma(const unsigned short* __restrict__ Qhi, const unsigned short* __restrict__ Qlo,
               const unsigned short* __restrict__ Khi, const unsigned short* __restrict__ Klo,
               const unsigned short* __restrict__ Vhi, const unsigned short* __restrict__ Vlo,
               unsigned short* __restrict__ Yh, unsigned short* __restrict__ Yl)
{
    __shared__ unsigned short KsH[64][72], KsL[64][72];
    __shared__ unsigned short VsH[64][72], VsL[64][72];

    const int t = threadIdx.x, lane = t & 63, w = t >> 6;
    const int bid = blockIdx.x;
    const int xcd = bid & 7, idx = bid >> 3;
    const int h = 2 * xcd + (idx >> 4);          // 2 heads per XCD (K/V L2-resident)
    const int pairI = idx & 15;
    const int l15 = lane & 15, lg = lane >> 4, dg = lg * 4;
    const int srow = t >> 2, q16 = t & 3;
    const int sc0 = (q16 >> 1) * 32 + 4 * (q16 & 1);   // permuted write base col

    u16x8 pf[8];

#pragma unroll 1
    for (int pass = 0; pass < 2; ++pass) {
        const int qt = pass ? (31 - pairI) : pairI;
        const int K0 = 2 * qt;
        const int ktmax = K0 + 1;

        // Q fragments: frag u rows qt*128 + u*64 + w*16 + l15
        bf16x8 qh[2][2], ql[2][2];
#pragma unroll
        for (int u = 0; u < 2; ++u) {
            const size_t qrow = ((size_t)h * SEQ + (size_t)qt * 128 + u * 64 + w * 16 + l15) * DK;
#pragma unroll
            for (int c = 0; c < 2; ++c) {
                FragU uh, ul;
                uh.q[0] = *reinterpret_cast<const ushort4*>(&Qhi[qrow + c * 32 + dg]);
                uh.q[1] = *reinterpret_cast<const ushort4*>(&Qhi[qrow + c * 32 + 16 + dg]);
                ul.q[0] = *reinterpret_cast<const ushort4*>(&Qlo[qrow + c * 32 + dg]);
                ul.q[1] = *reinterpret_cast<const ushort4*>(&Qlo[qrow + c * 32 + 16 + dg]);
                qh[u][c] = uh.b; ql[u][c] = ul.b;
            }
        }

        f32x4 yacc[2][4];
#pragma unroll
        for (int u = 0; u < 2; ++u)
#pragma unroll
            for (int dt = 0; dt < 4; ++dt) yacc[u][dt] = (f32x4){0.f, 0.f, 0.f, 0.f};
        float m_run[2] = {-1e30f, -1e30f}, l_run[2] = {0.f, 0.f};

        // prefetch kt=0
        {
            const size_t gK = ((size_t)h * SEQ + srow) * DK + q16 * 16;
            const size_t gV = ((size_t)h * DK + srow) * SEQ + q16 * 16;
            pf[0] = *reinterpret_cast<const u16x8*>(&Khi[gK]);
            pf[1] = *reinterpret_cast<const u16x8*>(&Khi[gK + 8]);
            pf[2] = *reinterpret_cast<const u16x8*>(&Klo[gK]);
            pf[3] = *reinterpret_cast<const u16x8*>(&Klo[gK + 8]);
            pf[4] = *reinterpret_cast<const u16x8*>(&Vhi[gV]);
            pf[5] = *reinterpret_cast<const u16x8*>(&Vhi[gV + 8]);
            pf[6] = *reinterpret_cast<const u16x8*>(&Vlo[gV]);
            pf[7] = *reinterpret_cast<const u16x8*>(&Vlo[gV + 8]);
        }

        for (int kt = 0; kt <= ktmax; ++kt) {
            __syncthreads();   // LDS free
            {
                FragU f0, f1;
                f0.u = pf[0]; f1.u = pf[1];
                *reinterpret_cast<ushort4*>(&KsH[srow][sc0])      = f0.q[0];
                *reinterpret_cast<ushort4*>(&KsH[srow][sc0 + 8])  = f0.q[1];
                *reinterpret_cast<ushort4*>(&KsH[srow][sc0 + 16]) = f1.q[0];
                *reinterpret_cast<ushort4*>(&KsH[srow][sc0 + 24]) = f1.q[1];
                f0.u = pf[2]; f1.u = pf[3];
                *reinterpret_cast<ushort4*>(&KsL[srow][sc0])      = f0.q[0];
                *reinterpret_cast<ushort4*>(&KsL[srow][sc0 + 8])  = f0.q[1];
                *reinterpret_cast<ushort4*>(&KsL[srow][sc0 + 16]) = f1.q[0];
                *reinterpret_cast<ushort4*>(&KsL[srow][sc0 + 24]) = f1.q[1];
                f0.u = pf[4]; f1.u = pf[5];
                *reinterpret_cast<ushort4*>(&VsH[srow][sc0])      = f0.q[0];
                *reinterpret_cast<ushort4*>(&VsH[srow][sc0 + 8])  = f0.q[1];
                *reinterpret_cast<ushort4*>(&VsH[srow][sc0 + 16]) = f1.q[0];
                *reinterpret_cast<ushort4*>(&VsH[srow][sc0 + 24]) = f1.q[1];
                f0.u = pf[6]; f1.u = pf[7];
                *reinterpret_cast<ushort4*>(&VsL[srow][sc0])      = f0.q[0];
                *reinterpret_cast<ushort4*>(&VsL[srow][sc0 + 8])  = f0.q[1];
                *reinterpret_cast<ushort4*>(&VsL[srow][sc0 + 16]) = f1.q[0];
                *reinterpret_cast<ushort4*>(&VsL[srow][sc0 + 24]) = f1.q[1];
            }
            __syncthreads();   // LDS ready

            if (kt < ktmax) {   // prefetch kt+1
                const size_t gK = ((size_t)h * SEQ + (size_t)(kt + 1) * 64 + srow) * DK + q16 * 16;
                const size_t gV = ((size_t)h * DK + srow) * SEQ + (size_t)(kt + 1) * 64 + q16 * 16;
                pf[0] = *reinterpret_cast<const u16x8*>(&Khi[gK]);
                pf[1] = *reinterpret_cast<const u16x8*>(&Khi[gK + 8]);
                pf[2] = *reinterpret_cast<const u16x8*>(&Klo[gK]);
                pf[3] = *reinterpret_cast<const u16x8*>(&Klo[gK + 8]);
                pf[4] = *reinterpret_cast<const u16x8*>(&Vhi[gV]);
                pf[5] = *reinterpret_cast<const u16x8*>(&Vhi[gV + 8]);
                pf[6] = *reinterpret_cast<const u16x8*>(&Vlo[gV]);
                pf[7] = *reinterpret_cast<const u16x8*>(&Vlo[gV + 8]);
            }

            const int mode0 = (kt < K0) ? 1 : ((kt == K0) ? 2 : 0);  // frag0
            const int mode1 = (kt <= K0) ? 1 : 2;                    // frag1
            const bool act0 = (mode0 != 0);

            // ---- S^T = K * Q^T, both frags share K fragment loads ----
            f32x4 st0[4], st1[4];
#pragma unroll
            for (int ktile = 0; ktile < 4; ++ktile) {
                const bool sk0 = !act0 || (mode0 == 2 && ktile > w);
                const bool sk1 = (mode1 == 2 && ktile > w);
                f32x4 s0 = (f32x4){0.f, 0.f, 0.f, 0.f};
                f32x4 s1 = (f32x4){0.f, 0.f, 0.f, 0.f};
                if (!sk0 || !sk1) {
#pragma unroll
                    for (int c = 0; c < 2; ++c) {
                        FragU kh, kl;
                        kh.u = *reinterpret_cast<const u16x8*>(&KsH[ktile * 16 + l15][c * 32 + 8 * lg]);
                        kl.u = *reinterpret_cast<const u16x8*>(&KsL[ktile * 16 + l15][c * 32 + 8 * lg]);
                        if (!sk0) {
                            s0 = __builtin_amdgcn_mfma_f32_16x16x32_bf16(kh.b, qh[0][c], s0, 0, 0, 0);
                            s0 = __builtin_amdgcn_mfma_f32_16x16x32_bf16(kh.b, ql[0][c], s0, 0, 0, 0);
                            s0 = __builtin_amdgcn_mfma_f32_16x16x32_bf16(kl.b, qh[0][c], s0, 0, 0, 0);
                        }
                        if (!sk1) {
                            s1 = __builtin_amdgcn_mfma_f32_16x16x32_bf16(kh.b, qh[1][c], s1, 0, 0, 0);
                            s1 = __builtin_amdgcn_mfma_f32_16x16x32_bf16(kh.b, ql[1][c], s1, 0, 0, 0);
                            s1 = __builtin_amdgcn_mfma_f32_16x16x32_bf16(kl.b, qh[1][c], s1, 0, 0, 0);
                        }
                    }
                }
                st0[ktile] = sk0 ? (f32x4){-1e30f, -1e30f, -1e30f, -1e30f} : s0;
                st1[ktile] = sk1 ? (f32x4){-1e30f, -1e30f, -1e30f, -1e30f} : s1;
            }

            // diagonal element masks (key = ktile*16+dg+r vs qrel = w*16+l15)
            if (mode0 == 2) {
#pragma unroll
                for (int ktile = 0; ktile < 4; ++ktile)
#pragma unroll
                    for (int r = 0; r < 4; ++r)
                        if (ktile * 16 + dg + r > w * 16 + l15) st0[ktile][r] = -1e30f;
            }
            if (mode1 == 2) {
#pragma unroll
                for (int ktile = 0; ktile < 4; ++ktile)
#pragma unroll
                    for (int r = 0; r < 4; ++r)
                        if (ktile * 16 + dg + r > w * 16 + l15) st1[ktile][r] = -1e30f;
            }

            // ---- online softmax (exp2 units, defer-max THR=11.5) ----
            bf16x8 pa0[2], pa1[2];
#pragma unroll
            for (int u = 0; u < 2; ++u) {
                if (u == 0 && !act0) continue;
                f32x4* st = (u == 0) ? st0 : st1;
                float rowmax = st[0][0];
#pragma unroll
                for (int ktile = 0; ktile < 4; ++ktile)
#pragma unroll
                    for (int r = 0; r < 4; ++r) rowmax = fmaxf(rowmax, st[ktile][r]);
                rowmax = fmaxf(rowmax, __shfl_xor(rowmax, 16));
                rowmax = fmaxf(rowmax, __shfl_xor(rowmax, 32));
                if (!__all(rowmax <= m_run[u] + 11.5f)) {
                    const float mnew = fmaxf(m_run[u], rowmax);
                    const float factor = fexp2(m_run[u] - mnew);
                    l_run[u] *= factor;
#pragma unroll
                    for (int r = 0; r < 4; ++r) {
                        const float fr = __shfl(factor, (lg << 2) | r);
#pragma unroll
                        for (int dt = 0; dt < 4; ++dt) yacc[u][dt][r] *= fr;
                    }
                    m_run[u] = mnew;
                }
                float p[4][4]; float psum = 0.f;
#pragma unroll
                for (int ktile = 0; ktile < 4; ++ktile)
#pragma unroll
                    for (int r = 0; r < 4; ++r) {
                        p[ktile][r] = fexp2(st[ktile][r] - m_run[u]);
                        psum += p[ktile][r];
                    }
                psum += __shfl_xor(psum, 16);
                psum += __shfl_xor(psum, 32);
                l_run[u] += psum;
#pragma unroll
                for (int c = 0; c < 2; ++c) {
                    FragU P;
                    P.w[0] = cvtpk(p[2 * c][0],     p[2 * c][1]);
                    P.w[1] = cvtpk(p[2 * c][2],     p[2 * c][3]);
                    P.w[2] = cvtpk(p[2 * c + 1][0], p[2 * c + 1][1]);
                    P.w[3] = cvtpk(p[2 * c + 1][2], p[2 * c + 1][3]);
                    if (u == 0) pa0[c] = P.b; else pa1[c] = P.b;
                }
            }

            // ---- y += P * V (2-term: P_rne * (vh + vl)), shared V loads ----
#pragma unroll
            for (int dt = 0; dt < 4; ++dt) {
#pragma unroll
                for (int c = 0; c < 2; ++c) {
                    FragU vh, vl;
                    vh.u = *reinterpret_cast<const u16x8*>(&VsH[dt * 16 + l15][c * 32 + 8 * lg]);
                    vl.u = *reinterpret_cast<const u16x8*>(&VsL[dt * 16 + l15][c * 32 + 8 * lg]);
                    if (act0) {
                        yacc[0][dt] = __builtin_amdgcn_mfma_f32_16x16x32_bf16(pa0[c], vh.b, yacc[0][dt], 0, 0, 0);
                        yacc[0][dt] = __builtin_amdgcn_mfma_f32_16x16x32_bf16(pa0[c], vl.b, yacc[0][dt], 0, 0, 0);
                    }
                    yacc[1][dt] = __builtin_amdgcn_mfma_f32_16x16x32_bf16(pa1[c], vh.b, yacc[1][dt], 0, 0, 0);
                    yacc[1][dt] = __builtin_amdgcn_mfma_f32_16x16x32_bf16(pa1[c], vl.b, yacc[1][dt], 0, 0, 0);
                }
            }
        } // kt

        // ---- epilogue: y row = qt*128 + u*64 + w*16 + lg*4 + r ----
#pragma unroll
        for (int u = 0; u < 2; ++u) {
            const float inv = 1.0f / l_run[u];
#pragma unroll
            for (int r = 0; r < 4; ++r) {
                const float ir = __shfl(inv, (lg << 2) | r);
                const size_t row = (size_t)qt * 128 + u * 64 + w * 16 + lg * 4 + r;
#pragma unroll
                for (int dt = 0; dt < 4; ++dt) {
                    unsigned short hh, ll;
                    split1(yacc[u][dt][r] * ir, hh, ll);
                    const size_t off = row * DM + h * DK + dt * 16 + l15;
                    Yh[off] = hh; Yl[off] = ll;
                }
            }
        }
    } // pass
}

// ---------------------------------------------------------------------------
extern "C" void kernel_launch(void* const* d_in, const int* in_sizes, int n_in,
                              void* d_out, int out_size, void* d_ws, size_t ws_size,
                              hipStream_t stream)
{
    const float* x    = (const float*)d_in[0];
    const float* Wq   = (const float*)d_in[1];
    const float* Wk   = (const float*)d_in[2];
    const float* Wv   = (const float*)d_in[3];
    const float* Wo   = (const float*)d_in[4];
    const float* cosT = (const float*)d_in[5];
    const float* sinT = (const float*)d_in[6];
    const int*   pos  = (const int*)d_in[7];
    float* out = (float*)d_out;

    // Workspace (64 MB): 8 bf16 arrays of SEQ*DM
    const size_t E = (size_t)SEQ * DM;
    unsigned short* qh = (unsigned short*)d_ws;
    unsigned short* ql = qh + E;
    unsigned short* kh = ql + E;
    unsigned short* kl = kh + E;
    unsigned short* vh = kl + E;
    unsigned short* vl = vh + E;
    unsigned short* yh = vl + E;
    unsigned short* yl = yh + E;

    gemm_mfma<4><<<dim3(768), dim3(256), 0, stream>>>(
        x, nullptr, nullptr, Wq, Wk, Wv,
        qh, ql, kh, kl, vh, vl, nullptr, cosT, sinT, pos);
    attn_mfma<<<dim3(256), dim3(256), 0, stream>>>(qh, ql, kh, kl, vh, vl, yh, yl);
    gemm_mfma<0><<<dim3(256), dim3(256), 0, stream>>>(
        nullptr, yh, yl, Wo, nullptr, nullptr,
        nullptr, nullptr, nullptr, nullptr, nullptr, nullptr, out, cosT, sinT, pos);
}